// Round 1
// baseline (457.951 us; speedup 1.0000x reference)
//
#include <hip/hip_runtime.h>
#include <hip/hip_bf16.h>

typedef __attribute__((ext_vector_type(8))) short short8;
typedef __attribute__((ext_vector_type(4))) float f32x4;
typedef unsigned short u16;

#define TTOK 4096
#define DMOD 512
#define DFFN 2048
#define NEXP 8
#define HEXP 1024

__device__ __forceinline__ u16 to_bf16(float f) {
    union { __hip_bfloat16 h; u16 u; } cv;
    cv.h = __float2bfloat16(f);
    return cv.u;
}

__device__ __forceinline__ float gelu_tanh(float x) {
    const float c = 0.7978845608028654f;
    float t = tanhf(c * (x + 0.044715f * x * x * x));
    return 0.5f * x * (1.0f + t);
}

// ---------------- transpose + fp32->bf16 cast: in [R,C] -> out [C,R] ----------------
__global__ __launch_bounds__(256) void transpose_cast(
    const float* __restrict__ in, u16* __restrict__ out, int R, int C)
{
    __shared__ float tile[32][33];
    size_t bo = (size_t)blockIdx.z * R * C;
    in += bo; out += bo;
    int c0 = blockIdx.x * 32, r0 = blockIdx.y * 32;
    int tx = threadIdx.x & 31, ty = threadIdx.x >> 5;
#pragma unroll
    for (int i = 0; i < 32; i += 8)
        tile[ty + i][tx] = in[(size_t)(r0 + ty + i) * C + c0 + tx];
    __syncthreads();
#pragma unroll
    for (int i = 0; i < 32; i += 8)
        out[(size_t)(c0 + ty + i) * R + r0 + tx] = to_bf16(tile[tx][ty + i]);
}

// ---------------- prep: LN(x2) + feat/film/FiLM + router top-2 + bucketing ----------------
__global__ __launch_bounds__(256) void prep_kernel(
    const float* __restrict__ hidden, const float* __restrict__ raw,
    const float* __restrict__ ln_g, const float* __restrict__ ln_b,
    const float* __restrict__ pre_g, const float* __restrict__ pre_b,
    const float* __restrict__ feat_w, const float* __restrict__ feat_b,
    const float* __restrict__ film_w, const float* __restrict__ film_b,
    const float* __restrict__ router_w, const float* __restrict__ router_b,
    u16* __restrict__ xs, u16* __restrict__ xin,
    int* __restrict__ cnt, int* __restrict__ slots, float* __restrict__ gl)
{
    const int t = blockIdx.x, tid = threadIdx.x;
    const int lane = tid & 63, wid = tid >> 6;
    __shared__ float sred[4], qred[4], raw_sh[16], feat_sh[64], logit_sh[8], plred[4][8];

    const float* hrow = hidden + (size_t)t * DMOD;
    float h0 = hrow[tid], h1 = hrow[tid + 256];
    float s = h0 + h1, q = h0 * h0 + h1 * h1;
#pragma unroll
    for (int off = 32; off > 0; off >>= 1) { s += __shfl_down(s, off); q += __shfl_down(q, off); }
    if (lane == 0) { sred[wid] = s; qred[wid] = q; }
    if (tid < 16) raw_sh[tid] = raw[(size_t)t * 16 + tid];
    __syncthreads();

    float mean = (sred[0] + sred[1] + sred[2] + sred[3]) * (1.0f / 512.0f);
    float var  = (qred[0] + qred[1] + qred[2] + qred[3]) * (1.0f / 512.0f) - mean * mean;
    float rstd = rsqrtf(var + 1e-5f);
    float xn0 = (h0 - mean) * rstd, xn1 = (h1 - mean) * rstd;
    float x0 = xn0 * ln_g[tid] + ln_b[tid];
    float x1 = xn1 * ln_g[tid + 256] + ln_b[tid + 256];
    xs[(size_t)t * DMOD + tid]       = to_bf16(xn0 * pre_g[tid] + pre_b[tid]);
    xs[(size_t)t * DMOD + tid + 256] = to_bf16(xn1 * pre_g[tid + 256] + pre_b[tid + 256]);

    // router partials (fp32, to keep top-2 decisions faithful to ref)
    float pl[8];
#pragma unroll
    for (int e = 0; e < 8; ++e)
        pl[e] = x0 * router_w[tid * 8 + e] + x1 * router_w[(tid + 256) * 8 + e];
#pragma unroll
    for (int e = 0; e < 8; ++e) {
        float v = pl[e];
#pragma unroll
        for (int off = 32; off > 0; off >>= 1) v += __shfl_down(v, off);
        if (lane == 0) plred[wid][e] = v;
    }

    // feat encoder: 64 outputs, K=16
    if (tid < 64) {
        float fv = feat_b[tid];
#pragma unroll
        for (int f = 0; f < 16; ++f) fv += raw_sh[f] * feat_w[f * 64 + tid];
        feat_sh[tid] = fv;
    }
    __syncthreads();

    if (tid < 8)
        logit_sh[tid] = plred[0][tid] + plred[1][tid] + plred[2][tid] + plred[3][tid] + router_b[tid];

    // film: each thread computes gamma(d0), gamma(d1), beta(d0), beta(d1)
    float f0 = film_b[tid], f1 = film_b[tid + 256], f2 = film_b[tid + 512], f3 = film_b[tid + 768];
    for (int j = 0; j < 64; ++j) {
        float fv = feat_sh[j];
        const float* fw = film_w + (size_t)j * 1024;
        f0 += fv * fw[tid]; f1 += fv * fw[tid + 256];
        f2 += fv * fw[tid + 512]; f3 += fv * fw[tid + 768];
    }
    xin[(size_t)t * DMOD + tid]       = to_bf16(x0 * (1.0f + f0) + f2);
    xin[(size_t)t * DMOD + tid + 256] = to_bf16(x1 * (1.0f + f1) + f3);
    __syncthreads();

    if (tid == 0) {
        float v0 = -1e30f, v1 = -1e30f; int i0 = 0, i1 = 0;
#pragma unroll
        for (int e = 0; e < 8; ++e) {
            float v = logit_sh[e];
            if (v > v0) { v1 = v0; i1 = i0; v0 = v; i0 = e; }
            else if (v > v1) { v1 = v; i1 = e; }
        }
        float g1 = 1.0f / (1.0f + expf(v0 - v1));
        float g0 = 1.0f - g1;
        int p0 = atomicAdd(&cnt[i0], 1);
        slots[i0 * TTOK + p0] = 2 * t;     gl[i0 * TTOK + p0] = g0;
        int p1 = atomicAdd(&cnt[i1], 1);
        slots[i1 * TTOK + p1] = 2 * t + 1; gl[i1 * TTOK + p1] = g1;
    }
}

// ---------------- shared 128x128 MFMA tile core ----------------
// A: bf16 [*, K] row-major (rows picked by grow0/grow1); Bt: bf16 [N, K] (B transposed)
__device__ __forceinline__ void gemm_tile(
    const u16* __restrict__ A, int K, int grow0, int grow1,
    const u16* __restrict__ Bt, int n0,
    f32x4 acc[4][4], u16* As, u16* Bs)
{
    const int tid = threadIdx.x;
    const int q8 = (tid & 3) * 8;
    const int r0 = tid >> 2;
    const u16* a0 = A + (size_t)grow0 * K + q8;
    const u16* a1 = A + (size_t)grow1 * K + q8;
    const u16* b0 = Bt + (size_t)(n0 + r0) * K + q8;
    const u16* b1 = Bt + (size_t)(n0 + r0 + 64) * K + q8;
    uint4* as0 = (uint4*)(As + (size_t)tid * 8);
    uint4* as1 = (uint4*)(As + (size_t)(tid + 256) * 8);
    uint4* bs0 = (uint4*)(Bs + (size_t)tid * 8);
    uint4* bs1 = (uint4*)(Bs + (size_t)(tid + 256) * 8);
#pragma unroll
    for (int mi = 0; mi < 4; ++mi)
#pragma unroll
        for (int nj = 0; nj < 4; ++nj) {
            acc[mi][nj][0] = 0.f; acc[mi][nj][1] = 0.f;
            acc[mi][nj][2] = 0.f; acc[mi][nj][3] = 0.f;
        }
    const int wid = tid >> 6, lane = tid & 63;
    const int wm = (wid >> 1) * 64, wn = (wid & 1) * 64;
    const int row16 = lane & 15, kq = (lane >> 4) * 8;

    for (int k0 = 0; k0 < K; k0 += 32) {
        *as0 = *(const uint4*)(a0 + k0);
        *as1 = *(const uint4*)(a1 + k0);
        *bs0 = *(const uint4*)(b0 + k0);
        *bs1 = *(const uint4*)(b1 + k0);
        __syncthreads();
        short8 af[4], bfr[4];
#pragma unroll
        for (int mi = 0; mi < 4; ++mi)
            af[mi] = *(const short8*)(As + (wm + mi * 16 + row16) * 32 + kq);
#pragma unroll
        for (int nj = 0; nj < 4; ++nj)
            bfr[nj] = *(const short8*)(Bs + (wn + nj * 16 + row16) * 32 + kq);
#pragma unroll
        for (int mi = 0; mi < 4; ++mi)
#pragma unroll
            for (int nj = 0; nj < 4; ++nj)
                acc[mi][nj] = __builtin_amdgcn_mfma_f32_16x16x32_bf16(af[mi], bfr[nj], acc[mi][nj], 0, 0, 0);
        __syncthreads();
    }
}

// ---------------- FFN1: h1 = gelu(xs @ fc1 + b) -> bf16 [T, DFF] ----------------
__global__ __launch_bounds__(256) void ffn1_kernel(
    const u16* __restrict__ xs, const u16* __restrict__ fc1t,
    const float* __restrict__ fc1_b, u16* __restrict__ h1)
{
    __shared__ u16 As[4096], Bs[4096];
    const int m0 = blockIdx.x * 128, n0 = blockIdx.y * 128;
    const int tid = threadIdx.x, r0 = tid >> 2;
    f32x4 acc[4][4];
    gemm_tile(xs, DMOD, m0 + r0, m0 + r0 + 64, fc1t, n0, acc, As, Bs);
    const int wid = tid >> 6, lane = tid & 63;
    const int wm = (wid >> 1) * 64, wn = (wid & 1) * 64;
    const int cb = lane & 15, rq = (lane >> 4) * 4;
#pragma unroll
    for (int mi = 0; mi < 4; ++mi)
#pragma unroll
        for (int nj = 0; nj < 4; ++nj) {
            int col = n0 + wn + nj * 16 + cb;
            float bias = fc1_b[col];
#pragma unroll
            for (int r = 0; r < 4; ++r) {
                int row = m0 + wm + mi * 16 + rq + r;
                h1[(size_t)row * DFFN + col] = to_bf16(gelu_tanh(acc[mi][nj][r] + bias));
            }
        }
}

// ---------------- FFN2: out = hidden + h1 @ fc2 + b ----------------
__global__ __launch_bounds__(256) void ffn2_kernel(
    const u16* __restrict__ h1, const u16* __restrict__ fc2t,
    const float* __restrict__ fc2_b, const float* __restrict__ hidden,
    float* __restrict__ out)
{
    __shared__ u16 As[4096], Bs[4096];
    const int m0 = blockIdx.x * 128, n0 = blockIdx.y * 128;
    const int tid = threadIdx.x, r0 = tid >> 2;
    f32x4 acc[4][4];
    gemm_tile(h1, DFFN, m0 + r0, m0 + r0 + 64, fc2t, n0, acc, As, Bs);
    const int wid = tid >> 6, lane = tid & 63;
    const int wm = (wid >> 1) * 64, wn = (wid & 1) * 64;
    const int cb = lane & 15, rq = (lane >> 4) * 4;
#pragma unroll
    for (int mi = 0; mi < 4; ++mi)
#pragma unroll
        for (int nj = 0; nj < 4; ++nj) {
            int col = n0 + wn + nj * 16 + cb;
            float bias = fc2_b[col];
#pragma unroll
            for (int r = 0; r < 4; ++r) {
                int row = m0 + wm + mi * 16 + rq + r;
                size_t idx = (size_t)row * DMOD + col;
                out[idx] = hidden[idx] + acc[mi][nj][r] + bias;
            }
        }
}

// ---------------- MoE1: hbuf[slot] = gelu(xin[token] @ w1[e] + b1[e]) ----------------
__global__ __launch_bounds__(256) void moe1_kernel(
    const u16* __restrict__ xin, const u16* __restrict__ w1t,
    const float* __restrict__ b1, const int* __restrict__ cnt,
    const int* __restrict__ slots, u16* __restrict__ hbuf)
{
    const int e = blockIdx.z;
    const int ce = cnt[e];
    const int m0 = blockIdx.x * 128;
    if (m0 >= ce) return;
    const int n0 = blockIdx.y * 128;
    const int* sl = slots + e * TTOK;
    __shared__ u16 As[4096], Bs[4096];
    const int tid = threadIdx.x, r0 = tid >> 2;
    int p0 = m0 + r0;      if (p0 > ce - 1) p0 = ce - 1;
    int p1 = m0 + r0 + 64; if (p1 > ce - 1) p1 = ce - 1;
    f32x4 acc[4][4];
    gemm_tile(xin, DMOD, sl[p0] >> 1, sl[p1] >> 1, w1t + (size_t)e * HEXP * DMOD, n0, acc, As, Bs);
    const int wid = tid >> 6, lane = tid & 63;
    const int wm = (wid >> 1) * 64, wn = (wid & 1) * 64;
    const int cb = lane & 15, rq = (lane >> 4) * 4;
#pragma unroll
    for (int mi = 0; mi < 4; ++mi)
#pragma unroll
        for (int r = 0; r < 4; ++r) {
            int p = m0 + wm + mi * 16 + rq + r;
            if (p < ce) {
                int slot = sl[p];
#pragma unroll
                for (int nj = 0; nj < 4; ++nj) {
                    int col = n0 + wn + nj * 16 + cb;
                    hbuf[(size_t)slot * HEXP + col] = to_bf16(gelu_tanh(acc[mi][nj][r] + b1[e * HEXP + col]));
                }
            }
        }
}

// ---------------- MoE2: moeo[slot] = gate * (hbuf[slot] @ w2[e] + b2[e]) ----------------
__global__ __launch_bounds__(256) void moe2_kernel(
    const u16* __restrict__ hbuf, const u16* __restrict__ w2t,
    const float* __restrict__ b2, const int* __restrict__ cnt,
    const int* __restrict__ slots, const float* __restrict__ gl,
    float* __restrict__ moeo)
{
    const int e = blockIdx.z;
    const int ce = cnt[e];
    const int m0 = blockIdx.x * 128;
    if (m0 >= ce) return;
    const int n0 = blockIdx.y * 128;
    const int* sl = slots + e * TTOK;
    const float* gle = gl + e * TTOK;
    __shared__ u16 As[4096], Bs[4096];
    const int tid = threadIdx.x, r0 = tid >> 2;
    int p0 = m0 + r0;      if (p0 > ce - 1) p0 = ce - 1;
    int p1 = m0 + r0 + 64; if (p1 > ce - 1) p1 = ce - 1;
    f32x4 acc[4][4];
    gemm_tile(hbuf, HEXP, sl[p0], sl[p1], w2t + (size_t)e * DMOD * HEXP, n0, acc, As, Bs);
    const int wid = tid >> 6, lane = tid & 63;
    const int wm = (wid >> 1) * 64, wn = (wid & 1) * 64;
    const int cb = lane & 15, rq = (lane >> 4) * 4;
#pragma unroll
    for (int mi = 0; mi < 4; ++mi)
#pragma unroll
        for (int r = 0; r < 4; ++r) {
            int p = m0 + wm + mi * 16 + rq + r;
            if (p < ce) {
                int slot = sl[p];
                float g = gle[p];
#pragma unroll
                for (int nj = 0; nj < 4; ++nj) {
                    int col = n0 + wn + nj * 16 + cb;
                    moeo[(size_t)slot * DMOD + col] = g * (acc[mi][nj][r] + b2[e * DMOD + col]);
                }
            }
        }
}

// ---------------- combine: out += alpha * (moe[2t] + moe[2t+1]) ----------------
__global__ __launch_bounds__(256) void combine_kernel(
    float* __restrict__ out, const float* __restrict__ moe, const float* __restrict__ alpha)
{
    int i = blockIdx.x * 256 + threadIdx.x;   // float4 index over T*D/4
    float a = alpha[0];
    const float4* m4 = (const float4*)moe;
    float4* o4 = (float4*)out;
    int tk = i >> 7, d4 = i & 127;
    float4 o = o4[i];
    float4 ma = m4[(size_t)tk * 256 + d4];
    float4 mb = m4[(size_t)tk * 256 + 128 + d4];
    o.x += a * (ma.x + mb.x); o.y += a * (ma.y + mb.y);
    o.z += a * (ma.z + mb.z); o.w += a * (ma.w + mb.w);
    o4[i] = o;
}

extern "C" void kernel_launch(void* const* d_in, const int* in_sizes, int n_in,
                              void* d_out, int out_size, void* d_ws, size_t ws_size,
                              hipStream_t stream)
{
    const float* hidden   = (const float*)d_in[0];
    const float* raw      = (const float*)d_in[1];
    const float* ln_g     = (const float*)d_in[2];
    const float* ln_b     = (const float*)d_in[3];
    const float* pre_g    = (const float*)d_in[4];
    const float* pre_b    = (const float*)d_in[5];
    const float* feat_w   = (const float*)d_in[6];
    const float* feat_b   = (const float*)d_in[7];
    const float* film_w   = (const float*)d_in[8];
    const float* film_b   = (const float*)d_in[9];
    const float* router_w = (const float*)d_in[10];
    const float* router_b = (const float*)d_in[11];
    const float* w1       = (const float*)d_in[12];
    const float* b1       = (const float*)d_in[13];
    const float* w2       = (const float*)d_in[14];
    const float* b2       = (const float*)d_in[15];
    const float* fc1_w    = (const float*)d_in[16];
    const float* fc1_b    = (const float*)d_in[17];
    const float* fc2_w    = (const float*)d_in[18];
    const float* fc2_b    = (const float*)d_in[19];
    const float* alpha    = (const float*)d_in[20];
    float* out = (float*)d_out;

    char* w = (char*)d_ws;
    auto alloc = [&](size_t b) { char* p = w; w += (b + 255) & ~(size_t)255; return p; };
    u16*  fc1t = (u16*)alloc((size_t)DFFN * DMOD * 2);
    u16*  fc2t = (u16*)alloc((size_t)DMOD * DFFN * 2);
    u16*  w1t  = (u16*)alloc((size_t)NEXP * HEXP * DMOD * 2);
    u16*  w2t  = (u16*)alloc((size_t)NEXP * DMOD * HEXP * 2);
    u16*  xs   = (u16*)alloc((size_t)TTOK * DMOD * 2);
    u16*  xin  = (u16*)alloc((size_t)TTOK * DMOD * 2);
    u16*  h1   = (u16*)alloc((size_t)TTOK * DFFN * 2);
    u16*  hb   = (u16*)alloc((size_t)2 * TTOK * HEXP * 2);
    float* moeo = (float*)alloc((size_t)2 * TTOK * DMOD * 4);
    int*   cnt  = (int*)alloc(NEXP * 4);
    int*   slots = (int*)alloc((size_t)NEXP * TTOK * 4);
    float* gl   = (float*)alloc((size_t)NEXP * TTOK * 4);

    hipMemsetAsync(cnt, 0, NEXP * 4, stream);
    transpose_cast<<<dim3(64, 16, 1), 256, 0, stream>>>(fc1_w, fc1t, 512, 2048);
    transpose_cast<<<dim3(16, 64, 1), 256, 0, stream>>>(fc2_w, fc2t, 2048, 512);
    transpose_cast<<<dim3(32, 16, 8), 256, 0, stream>>>(w1, w1t, 512, 1024);
    transpose_cast<<<dim3(16, 32, 8), 256, 0, stream>>>(w2, w2t, 1024, 512);
    prep_kernel<<<4096, 256, 0, stream>>>(hidden, raw, ln_g, ln_b, pre_g, pre_b,
        feat_w, feat_b, film_w, film_b, router_w, router_b, xs, xin, cnt, slots, gl);
    ffn1_kernel<<<dim3(32, 16), 256, 0, stream>>>(xs, fc1t, fc1_b, h1);
    ffn2_kernel<<<dim3(32, 4), 256, 0, stream>>>(h1, fc2t, fc2_b, hidden, out);
    moe1_kernel<<<dim3(32, 8, 8), 256, 0, stream>>>(xin, w1t, b1, cnt, slots, hb);
    moe2_kernel<<<dim3(32, 4, 8), 256, 0, stream>>>(hb, w2t, b2, cnt, slots, gl, moeo);
    combine_kernel<<<2048, 256, 0, stream>>>(out, moeo, alpha);
}

// Round 2
// 443.225 us; speedup vs baseline: 1.0332x; 1.0332x over previous
//
#include <hip/hip_runtime.h>
#include <hip/hip_bf16.h>

typedef __attribute__((ext_vector_type(8))) short short8;
typedef __attribute__((ext_vector_type(4))) float f32x4;
typedef unsigned short u16;

#define TTOK 4096
#define DMOD 512
#define DFFN 2048
#define NEXP 8
#define HEXP 1024

__device__ __forceinline__ u16 to_bf16(float f) {
    union { __hip_bfloat16 h; u16 u; } cv;
    cv.h = __float2bfloat16(f);
    return cv.u;
}

__device__ __forceinline__ float gelu_tanh(float x) {
    const float c = 0.7978845608028654f;
    float t = tanhf(c * (x + 0.044715f * x * x * x));
    return 0.5f * x * (1.0f + t);
}

// async global->LDS, 16B per lane; LDS dest = wave-uniform base + lane*16
__device__ __forceinline__ void gload16(const u16* g, u16* l) {
    __builtin_amdgcn_global_load_lds(
        (__attribute__((address_space(1))) void*)g,
        (__attribute__((address_space(3))) void*)l, 16, 0, 0);
}

// ---------------- all 4 weight transposes (fp32 [R,C] -> bf16 [C,R]) in ONE launch ----------------
__global__ __launch_bounds__(256) void transpose_all(
    const float* __restrict__ fc1_w, const float* __restrict__ fc2_w,
    const float* __restrict__ w1, const float* __restrict__ w2,
    u16* __restrict__ fc1t, u16* __restrict__ fc2t,
    u16* __restrict__ w1t, u16* __restrict__ w2t)
{
    __shared__ float tile[32][33];
    int b = blockIdx.x;
    const float* in; u16* out; int R, C, cb, rb;
    if (b < 1024)      { in = fc1_w; out = fc1t; R = 512;  C = 2048; cb = b & 63; rb = b >> 6; }
    else if (b < 2048) { b -= 1024; in = fc2_w; out = fc2t; R = 2048; C = 512;  cb = b & 15; rb = b >> 4; }
    else if (b < 6144) { b -= 2048; int z = b >> 9; b &= 511;
        in = w1 + (size_t)z * DMOD * HEXP; out = w1t + (size_t)z * DMOD * HEXP;
        R = 512;  C = 1024; cb = b & 31; rb = b >> 5; }
    else               { b -= 6144; int z = b >> 9; b &= 511;
        in = w2 + (size_t)z * HEXP * DMOD; out = w2t + (size_t)z * HEXP * DMOD;
        R = 1024; C = 512;  cb = b & 15; rb = b >> 4; }
    int c0 = cb * 32, r0 = rb * 32;
    int tx = threadIdx.x & 31, ty = threadIdx.x >> 5;
#pragma unroll
    for (int i = 0; i < 32; i += 8)
        tile[ty + i][tx] = in[(size_t)(r0 + ty + i) * C + c0 + tx];
    __syncthreads();
#pragma unroll
    for (int i = 0; i < 32; i += 8)
        out[(size_t)(c0 + ty + i) * R + r0 + tx] = to_bf16(tile[tx][ty + i]);
}

// ---------------- prep: LN(x2) + feat + router top-2 + bucketing (NO film loop) ----------------
__global__ __launch_bounds__(256) void prep_kernel(
    const float* __restrict__ hidden, const float* __restrict__ raw,
    const float* __restrict__ ln_g, const float* __restrict__ ln_b,
    const float* __restrict__ pre_g, const float* __restrict__ pre_b,
    const float* __restrict__ feat_w, const float* __restrict__ feat_b,
    const float* __restrict__ router_w, const float* __restrict__ router_b,
    u16* __restrict__ xs, float* __restrict__ xbuf, float* __restrict__ featbuf,
    int* __restrict__ cnt, int* __restrict__ slots, float* __restrict__ gl)
{
    const int t = blockIdx.x, tid = threadIdx.x;
    const int lane = tid & 63, wid = tid >> 6;
    __shared__ float sred[4], qred[4], raw_sh[16], logit_sh[8], plred[4][8];

    const float* hrow = hidden + (size_t)t * DMOD;
    float h0 = hrow[tid], h1 = hrow[tid + 256];
    float s = h0 + h1, q = h0 * h0 + h1 * h1;
#pragma unroll
    for (int off = 32; off > 0; off >>= 1) { s += __shfl_down(s, off); q += __shfl_down(q, off); }
    if (lane == 0) { sred[wid] = s; qred[wid] = q; }
    if (tid < 16) raw_sh[tid] = raw[(size_t)t * 16 + tid];
    __syncthreads();

    float mean = (sred[0] + sred[1] + sred[2] + sred[3]) * (1.0f / 512.0f);
    float var  = (qred[0] + qred[1] + qred[2] + qred[3]) * (1.0f / 512.0f) - mean * mean;
    float rstd = rsqrtf(var + 1e-5f);
    float xn0 = (h0 - mean) * rstd, xn1 = (h1 - mean) * rstd;
    float x0 = xn0 * ln_g[tid] + ln_b[tid];
    float x1 = xn1 * ln_g[tid + 256] + ln_b[tid + 256];
    xs[(size_t)t * DMOD + tid]       = to_bf16(xn0 * pre_g[tid] + pre_b[tid]);
    xs[(size_t)t * DMOD + tid + 256] = to_bf16(xn1 * pre_g[tid + 256] + pre_b[tid + 256]);
    xbuf[(size_t)t * DMOD + tid]       = x0;
    xbuf[(size_t)t * DMOD + tid + 256] = x1;

    // router partials in fp32 (top-2 decisions must match ref)
    float pl[8];
#pragma unroll
    for (int e = 0; e < 8; ++e)
        pl[e] = x0 * router_w[tid * 8 + e] + x1 * router_w[(tid + 256) * 8 + e];
#pragma unroll
    for (int e = 0; e < 8; ++e) {
        float v = pl[e];
#pragma unroll
        for (int off = 32; off > 0; off >>= 1) v += __shfl_down(v, off);
        if (lane == 0) plred[wid][e] = v;
    }

    if (tid < 64) {
        float fv = feat_b[tid];
#pragma unroll
        for (int f = 0; f < 16; ++f) fv += raw_sh[f] * feat_w[f * 64 + tid];
        featbuf[(size_t)t * 64 + tid] = fv;
    }
    __syncthreads();
    if (tid < 8)
        logit_sh[tid] = plred[0][tid] + plred[1][tid] + plred[2][tid] + plred[3][tid] + router_b[tid];
    __syncthreads();

    if (tid == 0) {
        float v0 = -1e30f, v1 = -1e30f; int i0 = 0, i1 = 0;
#pragma unroll
        for (int e = 0; e < 8; ++e) {
            float v = logit_sh[e];
            if (v > v0) { v1 = v0; i1 = i0; v0 = v; i0 = e; }
            else if (v > v1) { v1 = v; i1 = e; }
        }
        float g1 = 1.0f / (1.0f + expf(v0 - v1));
        float g0 = 1.0f - g1;
        int p0 = atomicAdd(&cnt[i0], 1);
        slots[i0 * TTOK + p0] = 2 * t;     gl[i0 * TTOK + p0] = g0;
        int p1 = atomicAdd(&cnt[i1], 1);
        slots[i1 * TTOK + p1] = 2 * t + 1; gl[i1 * TTOK + p1] = g1;
    }
}

// ---------------- film: xin = x*(1+gamma)+beta, tiled 16 tokens/block ----------------
// gamma|beta = feat @ film_w + film_b. Each thread owns cols {d, d+256} of gamma and beta.
__global__ __launch_bounds__(256) void film_kernel(
    const float* __restrict__ xbuf, const float* __restrict__ featbuf,
    const float* __restrict__ film_w, const float* __restrict__ film_b,
    u16* __restrict__ xin)
{
    const int t0 = blockIdx.x * 16, tid = threadIdx.x;
    __shared__ float fs[16 * 64];
#pragma unroll
    for (int i = 0; i < 4; ++i)
        fs[tid + i * 256] = featbuf[(size_t)t0 * 64 + tid + i * 256];
    __syncthreads();

    float acc[16][4];
#pragma unroll
    for (int t = 0; t < 16; ++t) { acc[t][0] = 0.f; acc[t][1] = 0.f; acc[t][2] = 0.f; acc[t][3] = 0.f; }

    for (int j = 0; j < 64; ++j) {
        const float* fw = film_w + (size_t)j * 1024 + tid;
        float w0 = fw[0], w1 = fw[256], w2 = fw[512], w3 = fw[768];
#pragma unroll
        for (int t = 0; t < 16; ++t) {
            float fv = fs[t * 64 + j];
            acc[t][0] += fv * w0; acc[t][1] += fv * w1;
            acc[t][2] += fv * w2; acc[t][3] += fv * w3;
        }
    }
    float b0 = film_b[tid], b1 = film_b[tid + 256], b2 = film_b[tid + 512], b3 = film_b[tid + 768];
#pragma unroll
    for (int t = 0; t < 16; ++t) {
        size_t row = (size_t)(t0 + t) * DMOD;
        float xv0 = xbuf[row + tid], xv1 = xbuf[row + tid + 256];
        xin[row + tid]       = to_bf16(xv0 * (1.0f + acc[t][0] + b0) + acc[t][2] + b2);
        xin[row + tid + 256] = to_bf16(xv1 * (1.0f + acc[t][1] + b1) + acc[t][3] + b3);
    }
}

// ---------------- shared 128x128 MFMA tile core (global_load_lds staging) ----------------
__device__ __forceinline__ void gemm_tile(
    const u16* __restrict__ A, int K, int grow0, int grow1,
    const u16* __restrict__ Bt, int n0,
    f32x4 acc[4][4], u16* As, u16* Bs)
{
    const int tid = threadIdx.x;
    const int q8 = (tid & 3) * 8;
    const int r0 = tid >> 2;
    const int wid = tid >> 6, lane = tid & 63;
    const u16* a0 = A + (size_t)grow0 * K + q8;
    const u16* a1 = A + (size_t)grow1 * K + q8;
    const u16* b0 = Bt + (size_t)(n0 + r0) * K + q8;
    const u16* b1 = Bt + (size_t)(n0 + r0 + 64) * K + q8;
    u16* asw = As + wid * 512;   // lane l lands at byte wid*1024 + l*16 == tid*16
    u16* bsw = Bs + wid * 512;
#pragma unroll
    for (int mi = 0; mi < 4; ++mi)
#pragma unroll
        for (int nj = 0; nj < 4; ++nj) {
            acc[mi][nj][0] = 0.f; acc[mi][nj][1] = 0.f;
            acc[mi][nj][2] = 0.f; acc[mi][nj][3] = 0.f;
        }
    const int wm = (wid >> 1) * 64, wn = (wid & 1) * 64;
    const int row16 = lane & 15, kq = (lane >> 4) * 8;

    for (int k0 = 0; k0 < K; k0 += 32) {
        gload16(a0 + k0, asw);
        gload16(a1 + k0, asw + 2048);
        gload16(b0 + k0, bsw);
        gload16(b1 + k0, bsw + 2048);
        __syncthreads();
        short8 af[4], bfr[4];
#pragma unroll
        for (int mi = 0; mi < 4; ++mi)
            af[mi] = *(const short8*)(As + (wm + mi * 16 + row16) * 32 + kq);
#pragma unroll
        for (int nj = 0; nj < 4; ++nj)
            bfr[nj] = *(const short8*)(Bs + (wn + nj * 16 + row16) * 32 + kq);
#pragma unroll
        for (int mi = 0; mi < 4; ++mi)
#pragma unroll
            for (int nj = 0; nj < 4; ++nj)
                acc[mi][nj] = __builtin_amdgcn_mfma_f32_16x16x32_bf16(af[mi], bfr[nj], acc[mi][nj], 0, 0, 0);
        __syncthreads();
    }
}

// ---------------- stage1: ffn1 (z==8) + moe1 (z<8) fused ----------------
__global__ __launch_bounds__(256) void stage1_kernel(
    const u16* __restrict__ xs, const u16* __restrict__ fc1t, const float* __restrict__ fc1_b,
    u16* __restrict__ h1,
    const u16* __restrict__ xin, const u16* __restrict__ w1t, const float* __restrict__ b1,
    const int* __restrict__ cnt, const int* __restrict__ slots, u16* __restrict__ hbuf)
{
    __shared__ __align__(16) u16 As[4096], Bs[4096];
    const int tid = threadIdx.x, r0 = tid >> 2;
    const int wid = tid >> 6, lane = tid & 63;
    const int wm = (wid >> 1) * 64, wn = (wid & 1) * 64;
    const int cb = lane & 15, rq = (lane >> 4) * 4;
    f32x4 acc[4][4];

    if (blockIdx.z == 8) {
        const int m0 = blockIdx.x * 128, n0 = blockIdx.y * 128;
        gemm_tile(xs, DMOD, m0 + r0, m0 + r0 + 64, fc1t, n0, acc, As, Bs);
#pragma unroll
        for (int mi = 0; mi < 4; ++mi)
#pragma unroll
            for (int nj = 0; nj < 4; ++nj) {
                int col = n0 + wn + nj * 16 + cb;
                float bias = fc1_b[col];
#pragma unroll
                for (int r = 0; r < 4; ++r) {
                    int row = m0 + wm + mi * 16 + rq + r;
                    h1[(size_t)row * DFFN + col] = to_bf16(gelu_tanh(acc[mi][nj][r] + bias));
                }
            }
    } else {
        if (blockIdx.y >= 8) return;
        const int e = blockIdx.z, ce = cnt[e];
        const int m0 = blockIdx.x * 128;
        if (m0 >= ce) return;
        const int n0 = blockIdx.y * 128;
        const int* sl = slots + e * TTOK;
        int p0 = m0 + r0;      if (p0 > ce - 1) p0 = ce - 1;
        int p1 = m0 + r0 + 64; if (p1 > ce - 1) p1 = ce - 1;
        gemm_tile(xin, DMOD, sl[p0] >> 1, sl[p1] >> 1, w1t + (size_t)e * HEXP * DMOD, n0, acc, As, Bs);
#pragma unroll
        for (int mi = 0; mi < 4; ++mi)
#pragma unroll
            for (int r = 0; r < 4; ++r) {
                int p = m0 + wm + mi * 16 + rq + r;
                if (p < ce) {
                    int slot = sl[p];
#pragma unroll
                    for (int nj = 0; nj < 4; ++nj) {
                        int col = n0 + wn + nj * 16 + cb;
                        hbuf[(size_t)slot * HEXP + col] = to_bf16(gelu_tanh(acc[mi][nj][r] + b1[e * HEXP + col]));
                    }
                }
            }
    }
}

// ---------------- stage2: ffn2 (z==8) + moe2 (z<8) fused ----------------
__global__ __launch_bounds__(256) void stage2_kernel(
    const u16* __restrict__ h1, const u16* __restrict__ fc2t, const float* __restrict__ fc2_b,
    const float* __restrict__ hidden, float* __restrict__ out,
    const u16* __restrict__ hbuf, const u16* __restrict__ w2t, const float* __restrict__ b2,
    const int* __restrict__ cnt, const int* __restrict__ slots, const float* __restrict__ gl,
    float* __restrict__ moeo)
{
    __shared__ __align__(16) u16 As[4096], Bs[4096];
    const int tid = threadIdx.x, r0 = tid >> 2;
    const int wid = tid >> 6, lane = tid & 63;
    const int wm = (wid >> 1) * 64, wn = (wid & 1) * 64;
    const int cb = lane & 15, rq = (lane >> 4) * 4;
    f32x4 acc[4][4];

    if (blockIdx.z == 8) {
        const int m0 = blockIdx.x * 128, n0 = blockIdx.y * 128;
        gemm_tile(h1, DFFN, m0 + r0, m0 + r0 + 64, fc2t, n0, acc, As, Bs);
#pragma unroll
        for (int mi = 0; mi < 4; ++mi)
#pragma unroll
            for (int nj = 0; nj < 4; ++nj) {
                int col = n0 + wn + nj * 16 + cb;
                float bias = fc2_b[col];
#pragma unroll
                for (int r = 0; r < 4; ++r) {
                    int row = m0 + wm + mi * 16 + rq + r;
                    size_t idx = (size_t)row * DMOD + col;
                    out[idx] = hidden[idx] + acc[mi][nj][r] + bias;
                }
            }
    } else {
        const int e = blockIdx.z, ce = cnt[e];
        const int m0 = blockIdx.x * 128;
        if (m0 >= ce) return;
        const int n0 = blockIdx.y * 128;
        const int* sl = slots + e * TTOK;
        const float* gle = gl + e * TTOK;
        int p0 = m0 + r0;      if (p0 > ce - 1) p0 = ce - 1;
        int p1 = m0 + r0 + 64; if (p1 > ce - 1) p1 = ce - 1;
        gemm_tile(hbuf, HEXP, sl[p0], sl[p1], w2t + (size_t)e * DMOD * HEXP, n0, acc, As, Bs);
#pragma unroll
        for (int mi = 0; mi < 4; ++mi)
#pragma unroll
            for (int r = 0; r < 4; ++r) {
                int p = m0 + wm + mi * 16 + rq + r;
                if (p < ce) {
                    int slot = sl[p];
                    float g = gle[p];
#pragma unroll
                    for (int nj = 0; nj < 4; ++nj) {
                        int col = n0 + wn + nj * 16 + cb;
                        moeo[(size_t)slot * DMOD + col] = g * (acc[mi][nj][r] + b2[e * DMOD + col]);
                    }
                }
            }
    }
}

// ---------------- combine: out += alpha * (moe[2t] + moe[2t+1]) ----------------
__global__ __launch_bounds__(256) void combine_kernel(
    float* __restrict__ out, const float* __restrict__ moe, const float* __restrict__ alpha)
{
    int i = blockIdx.x * 256 + threadIdx.x;   // float4 index over T*D/4
    float a = alpha[0];
    const float4* m4 = (const float4*)moe;
    float4* o4 = (float4*)out;
    int tk = i >> 7, d4 = i & 127;
    float4 o = o4[i];
    float4 ma = m4[(size_t)tk * 256 + d4];
    float4 mb = m4[(size_t)tk * 256 + 128 + d4];
    o.x += a * (ma.x + mb.x); o.y += a * (ma.y + mb.y);
    o.z += a * (ma.z + mb.z); o.w += a * (ma.w + mb.w);
    o4[i] = o;
}

extern "C" void kernel_launch(void* const* d_in, const int* in_sizes, int n_in,
                              void* d_out, int out_size, void* d_ws, size_t ws_size,
                              hipStream_t stream)
{
    const float* hidden   = (const float*)d_in[0];
    const float* raw      = (const float*)d_in[1];
    const float* ln_g     = (const float*)d_in[2];
    const float* ln_b     = (const float*)d_in[3];
    const float* pre_g    = (const float*)d_in[4];
    const float* pre_b    = (const float*)d_in[5];
    const float* feat_w   = (const float*)d_in[6];
    const float* feat_b   = (const float*)d_in[7];
    const float* film_w   = (const float*)d_in[8];
    const float* film_b   = (const float*)d_in[9];
    const float* router_w = (const float*)d_in[10];
    const float* router_b = (const float*)d_in[11];
    const float* w1       = (const float*)d_in[12];
    const float* b1       = (const float*)d_in[13];
    const float* w2       = (const float*)d_in[14];
    const float* b2       = (const float*)d_in[15];
    const float* fc1_w    = (const float*)d_in[16];
    const float* fc1_b    = (const float*)d_in[17];
    const float* fc2_w    = (const float*)d_in[18];
    const float* fc2_b    = (const float*)d_in[19];
    const float* alpha    = (const float*)d_in[20];
    float* out = (float*)d_out;

    char* w = (char*)d_ws;
    auto alloc = [&](size_t b) { char* p = w; w += (b + 255) & ~(size_t)255; return p; };
    u16*  fc1t = (u16*)alloc((size_t)DFFN * DMOD * 2);
    u16*  fc2t = (u16*)alloc((size_t)DMOD * DFFN * 2);
    u16*  w1t  = (u16*)alloc((size_t)NEXP * HEXP * DMOD * 2);
    u16*  w2t  = (u16*)alloc((size_t)NEXP * DMOD * HEXP * 2);
    u16*  xs   = (u16*)alloc((size_t)TTOK * DMOD * 2);
    u16*  xin  = (u16*)alloc((size_t)TTOK * DMOD * 2);
    u16*  h1   = (u16*)alloc((size_t)TTOK * DFFN * 2);
    u16*  hb   = (u16*)alloc((size_t)2 * TTOK * HEXP * 2);
    float* moeo = (float*)alloc((size_t)2 * TTOK * DMOD * 4);
    int*   cnt  = (int*)alloc(NEXP * 4);
    int*   slots = (int*)alloc((size_t)NEXP * TTOK * 4);
    float* gl   = (float*)alloc((size_t)NEXP * TTOK * 4);
    // lifetime-disjoint aliases (keep ws footprint == round 1):
    float* xbuf    = moeo;        // written by prep, read by film; moeo written in stage2
    float* featbuf = (float*)h1;  // written by prep, read by film; h1 written in stage1

    hipMemsetAsync(cnt, 0, NEXP * 4, stream);
    transpose_all<<<10240, 256, 0, stream>>>(fc1_w, fc2_w, w1, w2, fc1t, fc2t, w1t, w2t);
    prep_kernel<<<4096, 256, 0, stream>>>(hidden, raw, ln_g, ln_b, pre_g, pre_b,
        feat_w, feat_b, router_w, router_b, xs, xbuf, featbuf, cnt, slots, gl);
    film_kernel<<<256, 256, 0, stream>>>(xbuf, featbuf, film_w, film_b, xin);
    stage1_kernel<<<dim3(32, 16, 9), 256, 0, stream>>>(xs, fc1t, fc1_b, h1,
        xin, w1t, b1, cnt, slots, hb);
    stage2_kernel<<<dim3(32, 4, 9), 256, 0, stream>>>(h1, fc2t, fc2_b, hidden, out,
        hb, w2t, b2, cnt, slots, gl, moeo);
    combine_kernel<<<2048, 256, 0, stream>>>(out, moeo, alpha);
}

// Round 3
// 438.369 us; speedup vs baseline: 1.0447x; 1.0111x over previous
//
#include <hip/hip_runtime.h>
#include <hip/hip_bf16.h>

typedef __attribute__((ext_vector_type(8))) short short8;
typedef __attribute__((ext_vector_type(4))) float f32x4;
typedef unsigned short u16;

#define TTOK 4096
#define DMOD 512
#define DFFN 2048
#define NEXP 8
#define HEXP 1024

__device__ __forceinline__ u16 to_bf16(float f) {
    union { __hip_bfloat16 h; u16 u; } cv;
    cv.h = __float2bfloat16(f);
    return cv.u;
}

__device__ __forceinline__ float gelu_tanh(float x) {
    const float c = 0.7978845608028654f;
    float t = tanhf(c * (x + 0.044715f * x * x * x));
    return 0.5f * x * (1.0f + t);
}

__device__ __forceinline__ void gload16(const u16* g, u16* l) {
    __builtin_amdgcn_global_load_lds(
        (__attribute__((address_space(1))) void*)g,
        (__attribute__((address_space(3))) void*)l, 16, 0, 0);
}

__device__ __forceinline__ float4 ld_bf4(const u16* p) {
    ushort4 u = *(const ushort4*)p;
    union { unsigned i; float f; } a, b, c, d;
    a.i = (unsigned)u.x << 16; b.i = (unsigned)u.y << 16;
    c.i = (unsigned)u.z << 16; d.i = (unsigned)u.w << 16;
    return make_float4(a.f, b.f, c.f, d.f);
}

// ---------------- all 4 weight transposes (fp32 [R,C] -> bf16 [C,R]) in ONE launch ----------------
__global__ __launch_bounds__(256) void transpose_all(
    const float* __restrict__ fc1_w, const float* __restrict__ fc2_w,
    const float* __restrict__ w1, const float* __restrict__ w2,
    u16* __restrict__ fc1t, u16* __restrict__ fc2t,
    u16* __restrict__ w1t, u16* __restrict__ w2t)
{
    __shared__ float tile[32][33];
    int b = blockIdx.x;
    const float* in; u16* out; int R, C, cb, rb;
    if (b < 1024)      { in = fc1_w; out = fc1t; R = 512;  C = 2048; cb = b & 63; rb = b >> 6; }
    else if (b < 2048) { b -= 1024; in = fc2_w; out = fc2t; R = 2048; C = 512;  cb = b & 15; rb = b >> 4; }
    else if (b < 6144) { b -= 2048; int z = b >> 9; b &= 511;
        in = w1 + (size_t)z * DMOD * HEXP; out = w1t + (size_t)z * DMOD * HEXP;
        R = 512;  C = 1024; cb = b & 31; rb = b >> 5; }
    else               { b -= 6144; int z = b >> 9; b &= 511;
        in = w2 + (size_t)z * HEXP * DMOD; out = w2t + (size_t)z * HEXP * DMOD;
        R = 1024; C = 512;  cb = b & 15; rb = b >> 4; }
    int c0 = cb * 32, r0 = rb * 32;
    int tx = threadIdx.x & 31, ty = threadIdx.x >> 5;
#pragma unroll
    for (int i = 0; i < 32; i += 8)
        tile[ty + i][tx] = in[(size_t)(r0 + ty + i) * C + c0 + tx];
    __syncthreads();
#pragma unroll
    for (int i = 0; i < 32; i += 8)
        out[(size_t)(c0 + ty + i) * R + r0 + tx] = to_bf16(tile[tx][ty + i]);
}

// ---------------- prep: LN(x2) + feat + router top-2 + bucketing ----------------
__global__ __launch_bounds__(256) void prep_kernel(
    const float* __restrict__ hidden, const float* __restrict__ raw,
    const float* __restrict__ ln_g, const float* __restrict__ ln_b,
    const float* __restrict__ pre_g, const float* __restrict__ pre_b,
    const float* __restrict__ feat_w, const float* __restrict__ feat_b,
    const float* __restrict__ router_w, const float* __restrict__ router_b,
    u16* __restrict__ xs, float* __restrict__ xbuf, float* __restrict__ featbuf,
    int* __restrict__ cnt, int* __restrict__ slots,
    float* __restrict__ gslot, int* __restrict__ eslot)
{
    const int t = blockIdx.x, tid = threadIdx.x;
    const int lane = tid & 63, wid = tid >> 6;
    __shared__ float sred[4], qred[4], raw_sh[16], logit_sh[8], plred[4][8];

    const float* hrow = hidden + (size_t)t * DMOD;
    float h0 = hrow[tid], h1 = hrow[tid + 256];
    float s = h0 + h1, q = h0 * h0 + h1 * h1;
#pragma unroll
    for (int off = 32; off > 0; off >>= 1) { s += __shfl_down(s, off); q += __shfl_down(q, off); }
    if (lane == 0) { sred[wid] = s; qred[wid] = q; }
    if (tid < 16) raw_sh[tid] = raw[(size_t)t * 16 + tid];
    __syncthreads();

    float mean = (sred[0] + sred[1] + sred[2] + sred[3]) * (1.0f / 512.0f);
    float var  = (qred[0] + qred[1] + qred[2] + qred[3]) * (1.0f / 512.0f) - mean * mean;
    float rstd = rsqrtf(var + 1e-5f);
    float xn0 = (h0 - mean) * rstd, xn1 = (h1 - mean) * rstd;
    float x0 = xn0 * ln_g[tid] + ln_b[tid];
    float x1 = xn1 * ln_g[tid + 256] + ln_b[tid + 256];
    xs[(size_t)t * DMOD + tid]       = to_bf16(xn0 * pre_g[tid] + pre_b[tid]);
    xs[(size_t)t * DMOD + tid + 256] = to_bf16(xn1 * pre_g[tid + 256] + pre_b[tid + 256]);
    xbuf[(size_t)t * DMOD + tid]       = x0;
    xbuf[(size_t)t * DMOD + tid + 256] = x1;

    float pl[8];
#pragma unroll
    for (int e = 0; e < 8; ++e)
        pl[e] = x0 * router_w[tid * 8 + e] + x1 * router_w[(tid + 256) * 8 + e];
#pragma unroll
    for (int e = 0; e < 8; ++e) {
        float v = pl[e];
#pragma unroll
        for (int off = 32; off > 0; off >>= 1) v += __shfl_down(v, off);
        if (lane == 0) plred[wid][e] = v;
    }

    if (tid < 64) {
        float fv = feat_b[tid];
#pragma unroll
        for (int f = 0; f < 16; ++f) fv += raw_sh[f] * feat_w[f * 64 + tid];
        featbuf[(size_t)t * 64 + tid] = fv;
    }
    __syncthreads();
    if (tid < 8)
        logit_sh[tid] = plred[0][tid] + plred[1][tid] + plred[2][tid] + plred[3][tid] + router_b[tid];
    __syncthreads();

    if (tid == 0) {
        float v0 = -1e30f, v1 = -1e30f; int i0 = 0, i1 = 0;
#pragma unroll
        for (int e = 0; e < 8; ++e) {
            float v = logit_sh[e];
            if (v > v0) { v1 = v0; i1 = i0; v0 = v; i0 = e; }
            else if (v > v1) { v1 = v; i1 = e; }
        }
        float g1 = 1.0f / (1.0f + expf(v0 - v1));
        float g0 = 1.0f - g1;
        int p0 = atomicAdd(&cnt[i0], 1);
        slots[i0 * TTOK + p0] = 2 * t;
        int p1 = atomicAdd(&cnt[i1], 1);
        slots[i1 * TTOK + p1] = 2 * t + 1;
        gslot[2 * t] = g0;     eslot[2 * t] = i0;
        gslot[2 * t + 1] = g1; eslot[2 * t + 1] = i1;
    }
}

// ---------------- film: xin = x*(1+gamma)+beta, tiled 16 tokens/block ----------------
__global__ __launch_bounds__(256) void film_kernel(
    const float* __restrict__ xbuf, const float* __restrict__ featbuf,
    const float* __restrict__ film_w, const float* __restrict__ film_b,
    u16* __restrict__ xin)
{
    const int t0 = blockIdx.x * 16, tid = threadIdx.x;
    __shared__ float fs[16 * 64];
#pragma unroll
    for (int i = 0; i < 4; ++i)
        fs[tid + i * 256] = featbuf[(size_t)t0 * 64 + tid + i * 256];
    __syncthreads();

    float acc[16][4];
#pragma unroll
    for (int t = 0; t < 16; ++t) { acc[t][0] = 0.f; acc[t][1] = 0.f; acc[t][2] = 0.f; acc[t][3] = 0.f; }

    for (int j = 0; j < 64; ++j) {
        const float* fw = film_w + (size_t)j * 1024 + tid;
        float w0 = fw[0], w1 = fw[256], w2 = fw[512], w3 = fw[768];
#pragma unroll
        for (int t = 0; t < 16; ++t) {
            float fv = fs[t * 64 + j];
            acc[t][0] += fv * w0; acc[t][1] += fv * w1;
            acc[t][2] += fv * w2; acc[t][3] += fv * w3;
        }
    }
    float b0 = film_b[tid], b1 = film_b[tid + 256], b2 = film_b[tid + 512], b3 = film_b[tid + 768];
#pragma unroll
    for (int t = 0; t < 16; ++t) {
        size_t row = (size_t)(t0 + t) * DMOD;
        float xv0 = xbuf[row + tid], xv1 = xbuf[row + tid + 256];
        xin[row + tid]       = to_bf16(xv0 * (1.0f + acc[t][0] + b0) + acc[t][2] + b2);
        xin[row + tid + 256] = to_bf16(xv1 * (1.0f + acc[t][1] + b1) + acc[t][3] + b3);
    }
}

// ---------------- 128x128 MFMA tile core, BK=64, XOR-swizzled LDS ----------------
// LDS layout: row r (128B) holds its 8 16B-chunks permuted: chunk c at physical c^(r&7).
// Staging: wave w call c covers rows [w*32+c*8, +8): lane l -> row +(l>>3), phys chunk l&7,
//          global chunk (l&7)^((l>>3)&7). Contiguous 1KB per call; coalesced within rows.
// Reads: frag row r, chunk_log s*4+(lane>>4) -> phys ^(lane&7): 16 rows spread all 32 banks (2-way).
__device__ __forceinline__ void gemm64(
    const u16* __restrict__ A, int ldA,
    const u16* __restrict__ Bt, int ldB, int Klen,
    const int* arow, const int* brow,
    f32x4 acc[4][4], u16* As, u16* Bs)
{
    const int tid = threadIdx.x, lane = tid & 63, w = tid >> 6;
    const int cl = (lane & 7) ^ ((lane >> 3) & 7);
    const u16* ga[4]; const u16* gb[4];
#pragma unroll
    for (int c = 0; c < 4; ++c) {
        ga[c] = A + (size_t)arow[c] * ldA + cl * 8;
        gb[c] = Bt + (size_t)brow[c] * ldB + cl * 8;
    }
#pragma unroll
    for (int mi = 0; mi < 4; ++mi)
#pragma unroll
        for (int nj = 0; nj < 4; ++nj) {
            acc[mi][nj][0] = 0.f; acc[mi][nj][1] = 0.f;
            acc[mi][nj][2] = 0.f; acc[mi][nj][3] = 0.f;
        }
    const int wm = (w >> 1) * 64, wn = (w & 1) * 64;
    const int row16 = lane & 15, kc = lane >> 4, l7 = lane & 7;
    int aoff[4], boff[4];
#pragma unroll
    for (int mi = 0; mi < 4; ++mi) aoff[mi] = (wm + mi * 16 + row16) * 64;
#pragma unroll
    for (int nj = 0; nj < 4; ++nj) boff[nj] = (wn + nj * 16 + row16) * 64;
    const int cp0 = (kc ^ l7) * 8, cp1 = ((4 + kc) ^ l7) * 8;
    u16* asd = As + w * 2048;
    u16* bsd = Bs + w * 2048;

    for (int k0 = 0; k0 < Klen; k0 += 64) {
#pragma unroll
        for (int c = 0; c < 4; ++c) gload16(ga[c] + k0, asd + c * 512);
#pragma unroll
        for (int c = 0; c < 4; ++c) gload16(gb[c] + k0, bsd + c * 512);
        __syncthreads();
        short8 af[4], bfr[4];
#pragma unroll
        for (int mi = 0; mi < 4; ++mi) af[mi] = *(const short8*)(As + aoff[mi] + cp0);
#pragma unroll
        for (int nj = 0; nj < 4; ++nj) bfr[nj] = *(const short8*)(Bs + boff[nj] + cp0);
#pragma unroll
        for (int mi = 0; mi < 4; ++mi)
#pragma unroll
            for (int nj = 0; nj < 4; ++nj)
                acc[mi][nj] = __builtin_amdgcn_mfma_f32_16x16x32_bf16(af[mi], bfr[nj], acc[mi][nj], 0, 0, 0);
#pragma unroll
        for (int mi = 0; mi < 4; ++mi) af[mi] = *(const short8*)(As + aoff[mi] + cp1);
#pragma unroll
        for (int nj = 0; nj < 4; ++nj) bfr[nj] = *(const short8*)(Bs + boff[nj] + cp1);
#pragma unroll
        for (int mi = 0; mi < 4; ++mi)
#pragma unroll
            for (int nj = 0; nj < 4; ++nj)
                acc[mi][nj] = __builtin_amdgcn_mfma_f32_16x16x32_bf16(af[mi], bfr[nj], acc[mi][nj], 0, 0, 0);
        __syncthreads();
    }
}

// ---------------- stage1: ffn1 (z==8) + moe1 (z<8) ----------------
__global__ __launch_bounds__(256) void stage1_kernel(
    const u16* __restrict__ xs, const u16* __restrict__ fc1t, const float* __restrict__ fc1_b,
    u16* __restrict__ h1,
    const u16* __restrict__ xin, const u16* __restrict__ w1t, const float* __restrict__ b1,
    const int* __restrict__ cnt, const int* __restrict__ slots, u16* __restrict__ hbuf)
{
    __shared__ __align__(16) u16 As[8192], Bs[8192];
    const int tid = threadIdx.x, lane = tid & 63, w = tid >> 6;
    const int wm = (w >> 1) * 64, wn = (w & 1) * 64;
    const int cb = lane & 15, rq = (lane >> 4) * 4;
    const int rbase = w * 32 + (lane >> 3);
    int arow[4], brow[4];
    f32x4 acc[4][4];

    if (blockIdx.z == 8) {
        const int m0 = blockIdx.x * 128, n0 = blockIdx.y * 128;
#pragma unroll
        for (int c = 0; c < 4; ++c) { arow[c] = m0 + rbase + c * 8; brow[c] = n0 + rbase + c * 8; }
        gemm64(xs, DMOD, fc1t, DMOD, DMOD, arow, brow, acc, As, Bs);
#pragma unroll
        for (int mi = 0; mi < 4; ++mi)
#pragma unroll
            for (int nj = 0; nj < 4; ++nj) {
                int col = n0 + wn + nj * 16 + cb;
                float bias = fc1_b[col];
#pragma unroll
                for (int r = 0; r < 4; ++r) {
                    int row = m0 + wm + mi * 16 + rq + r;
                    h1[(size_t)row * DFFN + col] = to_bf16(gelu_tanh(acc[mi][nj][r] + bias));
                }
            }
    } else {
        if (blockIdx.y >= 8) return;
        const int e = blockIdx.z, ce = cnt[e];
        const int m0 = blockIdx.x * 128;
        if (m0 >= ce) return;
        const int n0 = blockIdx.y * 128;
        const int* sl = slots + e * TTOK;
#pragma unroll
        for (int c = 0; c < 4; ++c) {
            int p = m0 + rbase + c * 8; if (p > ce - 1) p = ce - 1;
            arow[c] = sl[p] >> 1;
            brow[c] = n0 + rbase + c * 8;
        }
        gemm64(xin, DMOD, w1t + (size_t)e * HEXP * DMOD, DMOD, DMOD, arow, brow, acc, As, Bs);
#pragma unroll
        for (int mi = 0; mi < 4; ++mi)
#pragma unroll
            for (int r = 0; r < 4; ++r) {
                int p = m0 + wm + mi * 16 + rq + r;
                if (p < ce) {
                    int slot = sl[p];
#pragma unroll
                    for (int nj = 0; nj < 4; ++nj) {
                        int col = n0 + wn + nj * 16 + cb;
                        hbuf[(size_t)slot * HEXP + col] = to_bf16(gelu_tanh(acc[mi][nj][r] + b1[e * HEXP + col]));
                    }
                }
            }
    }
}

// ---------------- stage2: ffn2 (z==8) + moe2 (z<8), split-K=2, bf16 partials ----------------
__global__ __launch_bounds__(256) void stage2_kernel(
    const u16* __restrict__ h1, const u16* __restrict__ fc2t,
    const u16* __restrict__ hbuf, const u16* __restrict__ w2t,
    const int* __restrict__ cnt, const int* __restrict__ slots,
    u16* __restrict__ pf, u16* __restrict__ pm)
{
    __shared__ __align__(16) u16 As[8192], Bs[8192];
    const int tid = threadIdx.x, lane = tid & 63, w = tid >> 6;
    const int wm = (w >> 1) * 64, wn = (w & 1) * 64;
    const int cb = lane & 15, rq = (lane >> 4) * 4;
    const int rbase = w * 32 + (lane >> 3);
    const int n0 = (blockIdx.y & 3) * 128, ks = blockIdx.y >> 2;
    int arow[4], brow[4];
    f32x4 acc[4][4];

    if (blockIdx.z == 8) {
        const int m0 = blockIdx.x * 128;
#pragma unroll
        for (int c = 0; c < 4; ++c) { arow[c] = m0 + rbase + c * 8; brow[c] = n0 + rbase + c * 8; }
        gemm64(h1 + ks * 1024, DFFN, fc2t + ks * 1024, DFFN, 1024, arow, brow, acc, As, Bs);
        u16* dst = pf + (size_t)ks * TTOK * DMOD;
#pragma unroll
        for (int mi = 0; mi < 4; ++mi)
#pragma unroll
            for (int nj = 0; nj < 4; ++nj) {
                int col = n0 + wn + nj * 16 + cb;
#pragma unroll
                for (int r = 0; r < 4; ++r) {
                    int row = m0 + wm + mi * 16 + rq + r;
                    dst[(size_t)row * DMOD + col] = to_bf16(acc[mi][nj][r]);
                }
            }
    } else {
        const int e = blockIdx.z, ce = cnt[e];
        const int m0 = blockIdx.x * 128;
        if (m0 >= ce) return;
        const int* sl = slots + e * TTOK;
#pragma unroll
        for (int c = 0; c < 4; ++c) {
            int p = m0 + rbase + c * 8; if (p > ce - 1) p = ce - 1;
            arow[c] = sl[p];
            brow[c] = n0 + rbase + c * 8;
        }
        gemm64(hbuf + ks * 512, HEXP, w2t + (size_t)e * DMOD * HEXP + ks * 512, HEXP, 512,
               arow, brow, acc, As, Bs);
        u16* dst = pm + (size_t)ks * 2 * TTOK * DMOD;
#pragma unroll
        for (int mi = 0; mi < 4; ++mi)
#pragma unroll
            for (int r = 0; r < 4; ++r) {
                int p = m0 + wm + mi * 16 + rq + r;
                if (p < ce) {
                    int slot = sl[p];
#pragma unroll
                    for (int nj = 0; nj < 4; ++nj) {
                        int col = n0 + wn + nj * 16 + cb;
                        dst[(size_t)slot * DMOD + col] = to_bf16(acc[mi][nj][r]);
                    }
                }
            }
    }
}

// ---------------- combine: out = hidden + ffn2(+bias) + alpha*(gated moe(+bias)) ----------------
__global__ __launch_bounds__(256) void combine_kernel(
    const float* __restrict__ hidden, const u16* __restrict__ pf, const u16* __restrict__ pm,
    const float* __restrict__ fc2_b, const float* __restrict__ b2,
    const float* __restrict__ gslot, const int* __restrict__ eslot,
    const float* __restrict__ alpha, float* __restrict__ out)
{
    int i = blockIdx.x * 256 + threadIdx.x;     // float4 index over T*D/4
    int t = i >> 7, d = (i & 127) * 4;
    float a = alpha[0];
    float4 h = ((const float4*)hidden)[i];
    float4 bias = *(const float4*)(fc2_b + d);

    size_t fo = (size_t)t * DMOD + d;
    float4 f0 = ld_bf4(pf + fo), f1 = ld_bf4(pf + (size_t)TTOK * DMOD + fo);

    int s0 = 2 * t, s1 = 2 * t + 1;
    float g0 = gslot[s0], g1 = gslot[s1];
    int e0 = eslot[s0], e1 = eslot[s1];
    size_t mo0 = (size_t)s0 * DMOD + d, mo1 = (size_t)s1 * DMOD + d;
    const u16* pm1 = pm + (size_t)2 * TTOK * DMOD;
    float4 ma = ld_bf4(pm + mo0), mb = ld_bf4(pm1 + mo0);
    float4 mc = ld_bf4(pm + mo1), md = ld_bf4(pm1 + mo1);
    float4 ba = *(const float4*)(b2 + e0 * DMOD + d);
    float4 bb = *(const float4*)(b2 + e1 * DMOD + d);

    float4 o;
    o.x = h.x + f0.x + f1.x + bias.x + a * (g0 * (ma.x + mb.x + ba.x) + g1 * (mc.x + md.x + bb.x));
    o.y = h.y + f0.y + f1.y + bias.y + a * (g0 * (ma.y + mb.y + ba.y) + g1 * (mc.y + md.y + bb.y));
    o.z = h.z + f0.z + f1.z + bias.z + a * (g0 * (ma.z + mb.z + ba.z) + g1 * (mc.z + md.z + bb.z));
    o.w = h.w + f0.w + f1.w + bias.w + a * (g0 * (ma.w + mb.w + ba.w) + g1 * (mc.w + md.w + bb.w));
    ((float4*)out)[i] = o;
}

extern "C" void kernel_launch(void* const* d_in, const int* in_sizes, int n_in,
                              void* d_out, int out_size, void* d_ws, size_t ws_size,
                              hipStream_t stream)
{
    const float* hidden   = (const float*)d_in[0];
    const float* raw      = (const float*)d_in[1];
    const float* ln_g     = (const float*)d_in[2];
    const float* ln_b     = (const float*)d_in[3];
    const float* pre_g    = (const float*)d_in[4];
    const float* pre_b    = (const float*)d_in[5];
    const float* feat_w   = (const float*)d_in[6];
    const float* feat_b   = (const float*)d_in[7];
    const float* film_w   = (const float*)d_in[8];
    const float* film_b   = (const float*)d_in[9];
    const float* router_w = (const float*)d_in[10];
    const float* router_b = (const float*)d_in[11];
    const float* w1       = (const float*)d_in[12];
    const float* b1       = (const float*)d_in[13];
    const float* w2       = (const float*)d_in[14];
    const float* b2       = (const float*)d_in[15];
    const float* fc1_w    = (const float*)d_in[16];
    const float* fc1_b    = (const float*)d_in[17];
    const float* fc2_w    = (const float*)d_in[18];
    const float* fc2_b    = (const float*)d_in[19];
    const float* alpha    = (const float*)d_in[20];
    float* out = (float*)d_out;

    char* w = (char*)d_ws;
    auto alloc = [&](size_t b) { char* p = w; w += (b + 255) & ~(size_t)255; return p; };
    u16*  fc1t = (u16*)alloc((size_t)DFFN * DMOD * 2);
    u16*  fc2t = (u16*)alloc((size_t)DMOD * DFFN * 2);
    u16*  w1t  = (u16*)alloc((size_t)NEXP * HEXP * DMOD * 2);
    u16*  w2t  = (u16*)alloc((size_t)NEXP * DMOD * HEXP * 2);
    u16*  xs   = (u16*)alloc((size_t)TTOK * DMOD * 2);
    u16*  xin  = (u16*)alloc((size_t)TTOK * DMOD * 2);
    u16*  h1   = (u16*)alloc((size_t)TTOK * DFFN * 2);
    u16*  hb   = (u16*)alloc((size_t)2 * TTOK * HEXP * 2);
    u16*  pf   = (u16*)alloc((size_t)2 * TTOK * DMOD * 2);        // ffn2 partials (2 splits)
    u16*  pm   = (u16*)alloc((size_t)2 * 2 * TTOK * DMOD * 2);    // moe2 partials (2 splits)
    int*   cnt   = (int*)alloc(NEXP * 4);
    int*   slots = (int*)alloc((size_t)NEXP * TTOK * 4);
    float* gslot = (float*)alloc((size_t)2 * TTOK * 4);
    int*   eslot = (int*)alloc((size_t)2 * TTOK * 4);
    float* xbuf  = (float*)pm;      // fp32 [T,D]=8MB, consumed by film before stage2 writes pm
    float* featbuf = (float*)h1;    // 1MB, consumed by film before stage1 writes h1

    hipMemsetAsync(cnt, 0, NEXP * 4, stream);
    transpose_all<<<10240, 256, 0, stream>>>(fc1_w, fc2_w, w1, w2, fc1t, fc2t, w1t, w2t);
    prep_kernel<<<4096, 256, 0, stream>>>(hidden, raw, ln_g, ln_b, pre_g, pre_b,
        feat_w, feat_b, router_w, router_b, xs, xbuf, featbuf, cnt, slots, gslot, eslot);
    film_kernel<<<256, 256, 0, stream>>>(xbuf, featbuf, film_w, film_b, xin);
    stage1_kernel<<<dim3(32, 16, 9), 256, 0, stream>>>(xs, fc1t, fc1_b, h1,
        xin, w1t, b1, cnt, slots, hb);
    stage2_kernel<<<dim3(32, 8, 9), 256, 0, stream>>>(h1, fc2t, hb, w2t, cnt, slots, pf, pm);
    combine_kernel<<<2048, 256, 0, stream>>>(hidden, pf, pm, fc2_b, b2, gslot, eslot, alpha, out);
}